// Round 3
// baseline (98.120 us; speedup 1.0000x reference)
//
#include <hip/hip_runtime.h>

// out = x * exp(betas), betas broadcast over 512 (b*c) planes.
// R2 restructure: split the grid by tensor (real | imag) so each wave has
// exactly ONE read stream + ONE write stream (copy-shaped, like the 6.3 TB/s
// ceiling benchmark), instead of 4 interleaved distant streams.
// Scale (betas load + expf) hoisted, loop-invariant per thread. Unroll 8
// keeps 8 nontemporal loads in flight per thread.

typedef float f32x4 __attribute__((ext_vector_type(4)));

__global__ __launch_bounds__(256) void diag_exp_scale_split(
    const f32x4* __restrict__ xr4,
    const f32x4* __restrict__ xi4,
    const f32x4* __restrict__ br4,
    const f32x4* __restrict__ bi4,
    f32x4* __restrict__ outr4,
    f32x4* __restrict__ outi4,
    int hw4,               // (h*w)/4 = 16384, power of two
    int planes_per_group,  // 16
    int nplanes,           // b*c = 512
    int blocks_per_tensor) // grid split point
{
    int blk = blockIdx.x;
    const f32x4* __restrict__ x;
    const f32x4* __restrict__ bet;
    f32x4* __restrict__ o;
    if (blk < blocks_per_tensor) {        // uniform branch (per-block)
        x = xr4;  bet = br4;  o = outr4;
    } else {
        x = xi4;  bet = bi4;  o = outi4;
        blk -= blocks_per_tensor;
    }

    int t = blk * blockDim.x + threadIdx.x;
    int m = t & (hw4 - 1);    // hw column owned by this thread
    int g = t / hw4;          // plane group

    f32x4 s = bet[m];         // one L2 load + 4 expf, hoisted
    s.x = __expf(s.x); s.y = __expf(s.y);
    s.z = __expf(s.z); s.w = __expf(s.w);

    int p0 = g * planes_per_group;
    int p1 = p0 + planes_per_group;
    if (p1 > nplanes) p1 = nplanes;

    #pragma unroll 8
    for (int p = p0; p < p1; ++p) {
        int idx = p * hw4 + m;            // max 8.4M, fits int
        f32x4 v = __builtin_nontemporal_load(&x[idx]);
        __builtin_nontemporal_store(v * s, &o[idx]);
    }
}

extern "C" void kernel_launch(void* const* d_in, const int* in_sizes, int n_in,
                              void* d_out, int out_size, void* d_ws, size_t ws_size,
                              hipStream_t stream) {
    const float* xr = (const float*)d_in[0];   // x_real  (b*c*h*w)
    const float* xi = (const float*)d_in[1];   // x_imag
    const float* br = (const float*)d_in[2];   // betas_real (h*w)
    const float* bi = (const float*)d_in[3];   // betas_imag

    float* out = (float*)d_out;
    int n    = in_sizes[0];        // 33,554,432
    int hw   = in_sizes[2];        // 65,536
    int hw4  = hw >> 2;            // 16,384
    int nplanes = n / hw;          // 512

    float* outr = out;             // tuple concat: out_real then out_imag
    float* outi = out + n;

    const int threads = 256;
    const int ngroups = 32;                         // 32 x 16 planes = 512
    int planes_per_group = (nplanes + ngroups - 1) / ngroups;
    int threads_per_tensor = hw4 * ngroups;         // 524,288
    int blocks_per_tensor = threads_per_tensor / threads;  // 2048
    int blocks = blocks_per_tensor * 2;             // 4096

    diag_exp_scale_split<<<blocks, threads, 0, stream>>>(
        (const f32x4*)xr, (const f32x4*)xi,
        (const f32x4*)br, (const f32x4*)bi,
        (f32x4*)outr, (f32x4*)outi,
        hw4, planes_per_group, nplanes, blocks_per_tensor);
}